// Round 3
// baseline (554.520 us; speedup 1.0000x reference)
//
#include <hip/hip_runtime.h>
#include <math.h>

#define WD 80
#define HW 6400
#define PW 82          // padded row width
#define PPX 6790       // allocated pixels per padded image (82*82=6724 + slack for staging over-read)
#define NIMG 8
#define NPAIR 32

typedef short bf16x8 __attribute__((ext_vector_type(8)));
typedef float f32x4 __attribute__((ext_vector_type(4)));

__device__ __forceinline__ float bf2f(unsigned short u) {
    return __uint_as_float(((unsigned)u) << 16);
}
__device__ __forceinline__ unsigned short f2bf(float f) {
    unsigned u = __float_as_uint(f);
    u += 0x7fff + ((u >> 16) & 1);          // RNE
    return (unsigned short)(u >> 16);
}

// ---------------- transformation matrices (inverse affine) ----------------
__global__ void prep_mats(const float* __restrict__ P, float* __restrict__ mats) {
    int p = threadIdx.x;
    if (p >= NPAIR) return;
    const float* m = P + p * 16;
    float m00 = m[0], m01 = m[1], m02 = m[3] / 0.8f;
    float m10 = m[4], m11 = m[5], m12 = m[7] / 0.8f;
    float cx = 40.0f, cy = 40.0f;
    float tx = cx - (m00 * cx + m01 * cy) + m02;
    float ty = cy - (m10 * cx + m11 * cy) + m12;
    float det = m00 * m11 - m01 * m10;
    float id = 1.0f / det;
    float a00 =  m11 * id, a01 = -m01 * id;
    float a10 = -m10 * id, a11 =  m00 * id;
    float a02 = -(a00 * tx + a01 * ty);
    float a12 = -(a10 * tx + a11 * ty);
    float* o = mats + p * 6;
    o[0] = a00; o[1] = a01; o[2] = a02;
    o[3] = a10; o[4] = a11; o[5] = a12;
}

// ---------------- nearest-neighbor validity mask (unpadded) ----------------
__global__ void make_mask(const float* __restrict__ mats, float* __restrict__ mask) {
    int p = blockIdx.x;
    const float* a = mats + p * 6;
    float a0 = a[0], a1 = a[1], a2 = a[2], a3 = a[3], a4 = a[4], a5 = a[5];
    for (int q = threadIdx.x; q < HW; q += blockDim.x) {
        float x = (float)(q % WD), y = (float)(q / WD);
        float sx = a0 * x + a1 * y + a2;
        float sy = a3 * x + a4 * y + a5;
        int ix = (int)rintf(sx), iy = (int)rintf(sy);
        mask[p * HW + q] = (ix >= 0 && ix < WD && iy >= 0 && iy < WD) ? 1.0f : 0.0f;
    }
}

// ---------------- zero fill ----------------
__global__ void zero_u4(uint4* __restrict__ p, int n4) {
    int t = blockIdx.x * blockDim.x + threadIdx.x;
    if (t < n4) p[t] = (uint4){0, 0, 0, 0};
}

// ---------------- initial rotation + CHW->HWC + pad + fp32->bf16 ----------------
// Ypad[img][row=a][col=b][c] = x[img][c][79-b][a]; border rows/cols zero.
__global__ void rot_init_pad(const float* __restrict__ x, unsigned short* __restrict__ Y) {
    int idx = blockIdx.x * blockDim.x + threadIdx.x;
    if (idx >= NIMG * 6724 * 8) return;
    int g = idx & 7;
    int pp = (idx >> 3) % 6724;
    int img = idx / (6724 * 8);
    int py = pp / PW, pxx = pp % PW;
    unsigned short r8[8] = {0, 0, 0, 0, 0, 0, 0, 0};
    if (py >= 1 && py <= 80 && pxx >= 1 && pxx <= 80) {
        int a = py - 1, bcol = pxx - 1;
        const float* src = x + (size_t)img * 64 * HW + (size_t)(79 - bcol) * WD + a;
#pragma unroll
        for (int k = 0; k < 8; ++k)
            r8[k] = f2bf(src[(size_t)(g * 8 + k) * HW]);
    }
    *(uint4*)(Y + ((size_t)img * PPX + pp) * 64 + g * 8) = *(const uint4*)r8;
}

// ---------------- weight repack: dst[tap][co][cin] bf16 ----------------
__global__ void prep_w(const float* __restrict__ src, unsigned short* __restrict__ dst,
                       int cin_n, int co_off, int ci_off, int co_stride) {
    int t = blockIdx.x * blockDim.x + threadIdx.x;
    if (t >= 9 * 64 * cin_n) return;
    int ci = t % cin_n;
    int co = (t / cin_n) & 63;
    int tap = t / (cin_n * 64);
    dst[t] = f2bf(src[(size_t)(co_off + co) * co_stride + (ci_off + ci) * 9 + tap]);
}

// ---------------- async halo-tile staging: 6 rows x 20 px x 64 ch bf16, swizzled ----------------
// LDS layout: granule (q,g) at lds[q*8 + (g ^ (q&7))], q = yl*20+xl.  Inverse permutation
// applied on the SOURCE address so global_load_lds's (uniform base + lane*16) lands right.
__device__ __forceinline__ void stage_tile(const unsigned short* __restrict__ src,
                                           int x0, int y0, uint4* lds, int tid) {
    const int lane = tid & 63;
    const int wv = tid >> 6;
    for (int c = wv; c < 15; c += 4) {
        int gi = c * 64 + lane;
        int q = gi >> 3;
        int yl = q / 20;
        int xl = q - yl * 20;
        int g = (gi & 7) ^ (q & 7);
        const unsigned short* gp = src + ((y0 + yl) * PW + x0 + xl) * 64 + g * 8;
        __builtin_amdgcn_global_load_lds(
            (const __attribute__((address_space(1))) unsigned int*)gp,
            (__attribute__((address_space(3))) unsigned int*)&lds[c * 64],
            16, 0, 0);
    }
}

// ---------------- ego conv: E = conv_e(y_t) + msg_b, f32 compact ----------------
__global__ __launch_bounds__(256) void ego_conv(const unsigned short* __restrict__ Y,
        const unsigned short* __restrict__ W, const float* __restrict__ bias,
        float* __restrict__ E, int only0) {
    __shared__ uint4 lds[960];
    const int tid = threadIdx.x, lane = tid & 63, wv = tid >> 6;
    const int ll = lane & 15, lh = lane >> 4;
    const int x0 = blockIdx.x * 16, y0 = blockIdx.y * 4;
    const int t = blockIdx.z;
    const int img = only0 ? t * 4 : t;
    stage_tile(Y + (size_t)img * PPX * 64, x0, y0, lds, tid);
    __syncthreads();
    f32x4 acc[4];
#pragma unroll
    for (int cg = 0; cg < 4; ++cg) acc[cg] = (f32x4){0.f, 0.f, 0.f, 0.f};
#pragma unroll
    for (int tap = 0; tap < 9; ++tap) {
        const int ty = tap / 3, tx = tap % 3;
#pragma unroll
        for (int ks = 0; ks < 2; ++ks) {
            const unsigned short* wb = W + (size_t)(tap * 64 + ll) * 64 + ks * 32 + lh * 8;
            bf16x8 Bf[4];
#pragma unroll
            for (int cg = 0; cg < 4; ++cg)
                Bf[cg] = *(const bf16x8*)(wb + (size_t)cg * 16 * 64);
            int q = (wv + ty) * 20 + tx + ll;
            int g = ks * 4 + lh;
            bf16x8 Af = *(const bf16x8*)&lds[q * 8 + (g ^ (q & 7))];
#pragma unroll
            for (int cg = 0; cg < 4; ++cg)
                acc[cg] = __builtin_amdgcn_mfma_f32_16x16x32_bf16(Af, Bf[cg], acc[cg], 0, 0, 0);
        }
    }
    int y = y0 + wv;
#pragma unroll
    for (int cg = 0; cg < 4; ++cg) {
        int co = cg * 16 + ll;
        float bv = bias[co];
#pragma unroll
        for (int j = 0; j < 4; ++j) {
            int x = x0 + lh * 4 + j;
            E[((size_t)t * HW + y * WD + x) * 64 + co] = acc[cg][j] + bv;
        }
    }
}

// ---------------- bilinear warp of all pairs into padded warped[k] ----------------
__global__ void warp_pairs(const unsigned short* __restrict__ Ysrc, const float* __restrict__ mats,
                           unsigned short* __restrict__ warped, int total, int only0) {
    int idx = blockIdx.x * blockDim.x + threadIdx.x;
    if (idx >= total) return;
    int g = idx & 7;
    int pp = (idx >> 3) % 6724;
    int k = idx / (6724 * 8);
    int p = only0 ? k * 4 : k;
    int py = pp / PW, pxx = pp % PW;
    uint4 v = {0, 0, 0, 0};
    if (py >= 1 && py <= 80 && pxx >= 1 && pxx <= 80) {
        int y = py - 1, x = pxx - 1;
        const float* a = mats + p * 6;
        float sx = a[0] * x + a[1] * y + a[2];
        float sy = a[3] * x + a[4] * y + a[5];
        float fxf = floorf(sx), fyf = floorf(sy);
        float fx = sx - fxf, fy = sy - fyf;
        int ix = (int)fxf, iy = (int)fyf;
        float w00 = (1.f - fx) * (1.f - fy), w10 = fx * (1.f - fy);
        float w01 = (1.f - fx) * fy,         w11 = fx * fy;
        bool vx0 = (unsigned)ix < WD, vx1 = (unsigned)(ix + 1) < WD;
        bool vy0 = (unsigned)iy < WD, vy1 = (unsigned)(iy + 1) < WD;
        if (!(vx0 && vy0)) w00 = 0.f;
        if (!(vx1 && vy0)) w10 = 0.f;
        if (!(vx0 && vy1)) w01 = 0.f;
        if (!(vx1 && vy1)) w11 = 0.f;
        int cx0 = min(max(ix, 0), WD - 1), cx1 = min(max(ix + 1, 0), WD - 1);
        int cy0 = min(max(iy, 0), WD - 1), cy1 = min(max(iy + 1, 0), WD - 1);
        const unsigned short* src = Ysrc + (size_t)(p >> 2) * PPX * 64 + g * 8;
        uint4 c00 = *(const uint4*)(src + ((cy0 + 1) * PW + cx0 + 1) * 64);
        uint4 c10 = *(const uint4*)(src + ((cy0 + 1) * PW + cx1 + 1) * 64);
        uint4 c01 = *(const uint4*)(src + ((cy1 + 1) * PW + cx0 + 1) * 64);
        uint4 c11 = *(const uint4*)(src + ((cy1 + 1) * PW + cx1 + 1) * 64);
        const unsigned short* p00 = (const unsigned short*)&c00;
        const unsigned short* p10 = (const unsigned short*)&c10;
        const unsigned short* p01 = (const unsigned short*)&c01;
        const unsigned short* p11 = (const unsigned short*)&c11;
        unsigned short r8[8];
#pragma unroll
        for (int kk = 0; kk < 8; ++kk) {
            float vv = w00 * bf2f(p00[kk]) + w10 * bf2f(p10[kk])
                     + w01 * bf2f(p01[kk]) + w11 * bf2f(p11[kk]);
            r8[kk] = f2bf(vv);
        }
        v = *(const uint4*)r8;
    }
    *(uint4*)(warped + ((size_t)k * PPX + pp) * 64 + g * 8) = v;
}

// ---------------- agg: Gpad[t] = 0.25*(sum_i m_i*conv_n(warped) + (sum m_i)*E) ----------------
__global__ __launch_bounds__(256) void msg_agg(const unsigned short* __restrict__ warped,
        const float* __restrict__ E, const float* __restrict__ mask,
        const unsigned short* __restrict__ W, unsigned short* __restrict__ Gpad, int only0) {
    __shared__ uint4 lds[960];
    __shared__ int flag;
    const int tid = threadIdx.x, lane = tid & 63, wv = tid >> 6;
    const int ll = lane & 15, lh = lane >> 4;
    const int x0 = blockIdx.x * 16, y0 = blockIdx.y * 4;
    const int t = blockIdx.z;
    const int b = only0 ? t : (t >> 2);
    const int j = only0 ? 0 : (t & 3);
    const int y = y0 + wv;

    f32x4 tot[4];
    f32x4 msum = (f32x4){0.f, 0.f, 0.f, 0.f};
#pragma unroll
    for (int cg = 0; cg < 4; ++cg) tot[cg] = (f32x4){0.f, 0.f, 0.f, 0.f};

    for (int i = 0; i < 4; ++i) {
        int k = only0 ? (b * 4 + i) : ((b * 4 + i) * 4 + j);
        int p = only0 ? k * 4 : k;
        const float* mk = mask + (size_t)p * HW + y * WD;
        float mv[4];
#pragma unroll
        for (int j2 = 0; j2 < 4; ++j2) mv[j2] = mk[x0 + lh * 4 + j2];
        if (tid == 0) flag = 0;
        __syncthreads();
        if (mv[0] != 0.f || mv[1] != 0.f || mv[2] != 0.f || mv[3] != 0.f) flag = 1;
        __syncthreads();
        if (!flag) continue;

        stage_tile(warped + (size_t)k * PPX * 64, x0, y0, lds, tid);
        __syncthreads();
        f32x4 acc[4];
#pragma unroll
        for (int cg = 0; cg < 4; ++cg) acc[cg] = (f32x4){0.f, 0.f, 0.f, 0.f};
#pragma unroll
        for (int tap = 0; tap < 9; ++tap) {
            const int ty = tap / 3, tx = tap % 3;
#pragma unroll
            for (int ks = 0; ks < 2; ++ks) {
                const unsigned short* wb = W + (size_t)(tap * 64 + ll) * 64 + ks * 32 + lh * 8;
                bf16x8 Bf[4];
#pragma unroll
                for (int cg = 0; cg < 4; ++cg)
                    Bf[cg] = *(const bf16x8*)(wb + (size_t)cg * 16 * 64);
                int q = (wv + ty) * 20 + tx + ll;
                int g = ks * 4 + lh;
                bf16x8 Af = *(const bf16x8*)&lds[q * 8 + (g ^ (q & 7))];
#pragma unroll
                for (int cg = 0; cg < 4; ++cg)
                    acc[cg] = __builtin_amdgcn_mfma_f32_16x16x32_bf16(Af, Bf[cg], acc[cg], 0, 0, 0);
            }
        }
        __syncthreads();   // protect lds before next i's staging
#pragma unroll
        for (int j2 = 0; j2 < 4; ++j2) {
            msum[j2] += mv[j2];
#pragma unroll
            for (int cg = 0; cg < 4; ++cg) tot[cg][j2] += mv[j2] * acc[cg][j2];
        }
    }
#pragma unroll
    for (int cg = 0; cg < 4; ++cg) {
        int co = cg * 16 + ll;
#pragma unroll
        for (int j2 = 0; j2 < 4; ++j2) {
            int x = x0 + lh * 4 + j2;
            float e = E[((size_t)t * HW + y * WD + x) * 64 + co];
            float val = 0.25f * (tot[cg][j2] + msum[j2] * e);
            Gpad[((size_t)t * PPX + (y + 1) * PW + x + 1) * 64 + co] = f2bf(val);
        }
    }
}

// ---------------- fused GRU conv: h1 = sigmoid(convU([y|G])+bU) * tanh(convC([y|G])+bC) ----------------
__global__ __launch_bounds__(256) void gru_conv(const unsigned short* __restrict__ Ysrc,
        const unsigned short* __restrict__ Gpad,
        const unsigned short* __restrict__ Wu, const unsigned short* __restrict__ Wc,
        const float* __restrict__ bu, const float* __restrict__ bc,
        unsigned short* __restrict__ Ydst, int only0) {
    __shared__ uint4 lds[960];
    const int tid = threadIdx.x, lane = tid & 63, wv = tid >> 6;
    const int ll = lane & 15, lh = lane >> 4;
    const int x0 = blockIdx.x * 16, y0 = blockIdx.y * 4;
    const int t = blockIdx.z;
    const int img = only0 ? t * 4 : t;

    f32x4 acc[8];
#pragma unroll
    for (int cg = 0; cg < 8; ++cg) acc[cg] = (f32x4){0.f, 0.f, 0.f, 0.f};

    for (int pass = 0; pass < 2; ++pass) {
        const unsigned short* src = pass ? (Gpad + (size_t)t * PPX * 64)
                                         : (Ysrc + (size_t)img * PPX * 64);
        if (pass) __syncthreads();
        stage_tile(src, x0, y0, lds, tid);
        __syncthreads();
#pragma unroll
        for (int tap = 0; tap < 9; ++tap) {
            const int ty = tap / 3, tx = tap % 3;
#pragma unroll
            for (int ks = 0; ks < 2; ++ks) {
                int woff = pass * 64 + ks * 32 + lh * 8;
                bf16x8 Bu[4], Bc[4];
#pragma unroll
                for (int cg = 0; cg < 4; ++cg) {
                    size_t wi = (size_t)(tap * 64 + cg * 16 + ll) * 128 + woff;
                    Bu[cg] = *(const bf16x8*)(Wu + wi);
                    Bc[cg] = *(const bf16x8*)(Wc + wi);
                }
                int q = (wv + ty) * 20 + tx + ll;
                int g = ks * 4 + lh;
                bf16x8 Af = *(const bf16x8*)&lds[q * 8 + (g ^ (q & 7))];
#pragma unroll
                for (int cg = 0; cg < 4; ++cg) {
                    acc[cg]     = __builtin_amdgcn_mfma_f32_16x16x32_bf16(Af, Bu[cg], acc[cg], 0, 0, 0);
                    acc[4 + cg] = __builtin_amdgcn_mfma_f32_16x16x32_bf16(Af, Bc[cg], acc[4 + cg], 0, 0, 0);
                }
            }
        }
    }
    int y = y0 + wv;
#pragma unroll
    for (int cg = 0; cg < 4; ++cg) {
        int co = cg * 16 + ll;
        float ub = bu[co], cb = bc[co];
#pragma unroll
        for (int j = 0; j < 4; ++j) {
            int x = x0 + lh * 4 + j;
            float u = 1.f / (1.f + expf(-(acc[cg][j] + ub)));
            float c = tanhf(acc[4 + cg][j] + cb);
            Ydst[((size_t)img * PPX + (y + 1) * PW + x + 1) * 64 + co] = f2bf(u * c);
        }
    }
}

// ---------------- final: out[b,h,w,o] = sum_c Ypad[4b][w][79-h][c]*mlp_w[o,c] + mlp_b[o] ----------------
__global__ void final_mlp(const unsigned short* __restrict__ yfin, const float* __restrict__ mw,
                          const float* __restrict__ mb, float* __restrict__ out) {
    int t = blockIdx.x * blockDim.x + threadIdx.x;
    if (t >= 2 * HW * 64) return;
    int o  = t & 63;
    int wv = (t >> 6) % WD;
    int h  = ((t >> 6) / WD) % WD;
    int b  = t / (HW * 64);
    const unsigned short* src = yfin + ((size_t)(b * 4) * PPX + (wv + 1) * PW + (80 - h)) * 64;
    float r = mb[o];
#pragma unroll 8
    for (int c = 0; c < 64; ++c) r += bf2f(src[c]) * mw[o * 64 + c];
    out[t] = r;
}

extern "C" void kernel_launch(void* const* d_in, const int* in_sizes, int n_in,
                              void* d_out, int out_size, void* d_ws, size_t ws_size,
                              hipStream_t stream) {
    const float* x       = (const float*)d_in[0];
    const float* P       = (const float*)d_in[2];
    const float* msg_w   = (const float*)d_in[4];
    const float* msg_b   = (const float*)d_in[5];
    const float* gates_w = (const float*)d_in[6];
    const float* gates_b = (const float*)d_in[7];
    const float* can_w   = (const float*)d_in[8];
    const float* can_b   = (const float*)d_in[9];
    const float* mlp_w   = (const float*)d_in[10];
    const float* mlp_b   = (const float*)d_in[11];
    float* out = (float*)d_out;

    char* wsb = (char*)d_ws;
    float* mats = (float*)wsb;                                  // 768 B (pad to 1024)
    float* mask = (float*)(wsb + 1024);                         // 819200
    unsigned short* Wn = (unsigned short*)(wsb + 820224);       // 73728
    unsigned short* We = Wn + 36864;                            // 73728
    unsigned short* Wu = We + 36864;                            // 147456
    unsigned short* Wc = Wu + 73728;                            // 147456
    unsigned short* Y0 = Wc + 73728;                            // 8*PPX*128 = 6952960
    unsigned short* Y1 = Y0 + (size_t)NIMG * PPX * 64;
    unsigned short* warped = Y1 + (size_t)NIMG * PPX * 64;      // 32*PPX*128 = 27811840
    unsigned short* Gpad = warped + (size_t)NPAIR * PPX * 64;   // 6952960
    float* E = (float*)(Gpad + (size_t)NIMG * PPX * 64);        // 13107200  (total ~63 MB)

    prep_mats<<<1, 64, 0, stream>>>(P, mats);
    make_mask<<<NPAIR, 256, 0, stream>>>(mats, mask);
    prep_w<<<(9 * 64 * 64 + 255) / 256, 256, 0, stream>>>(msg_w, Wn, 64, 0, 0, 1152);
    prep_w<<<(9 * 64 * 64 + 255) / 256, 256, 0, stream>>>(msg_w, We, 64, 0, 64, 1152);
    prep_w<<<(9 * 64 * 128 + 255) / 256, 256, 0, stream>>>(gates_w, Wu, 128, 64, 0, 1728);
    prep_w<<<(9 * 64 * 128 + 255) / 256, 256, 0, stream>>>(can_w, Wc, 128, 0, 0, 1728);
    zero_u4<<<((NIMG * PPX * 128 / 16) + 255) / 256, 256, 0, stream>>>((uint4*)Y1, NIMG * PPX * 128 / 16);
    rot_init_pad<<<(NIMG * 6724 * 8 + 255) / 256, 256, 0, stream>>>(x, Y0);

    // ---- iteration 0 (all 8 targets) ----
    ego_conv<<<dim3(5, 20, 8), 256, 0, stream>>>(Y0, We, msg_b, E, 0);
    warp_pairs<<<(32 * 6724 * 8 + 255) / 256, 256, 0, stream>>>(Y0, mats, warped, 32 * 6724 * 8, 0);
    msg_agg<<<dim3(5, 20, 8), 256, 0, stream>>>(warped, E, mask, Wn, Gpad, 0);
    gru_conv<<<dim3(5, 20, 8), 256, 0, stream>>>(Y0, Gpad, Wu, Wc, gates_b + 64, can_b, Y1, 0);

    // ---- iteration 1 (only j=0 targets: images 0 and 4) ----
    ego_conv<<<dim3(5, 20, 2), 256, 0, stream>>>(Y1, We, msg_b, E, 1);
    warp_pairs<<<(8 * 6724 * 8 + 255) / 256, 256, 0, stream>>>(Y1, mats, warped, 8 * 6724 * 8, 1);
    msg_agg<<<dim3(5, 20, 2), 256, 0, stream>>>(warped, E, mask, Wn, Gpad, 1);
    gru_conv<<<dim3(5, 20, 2), 256, 0, stream>>>(Y1, Gpad, Wu, Wc, gates_b + 64, can_b, Y0, 1);

    final_mlp<<<(2 * HW * 64 + 255) / 256, 256, 0, stream>>>(Y0, mlp_w, mlp_b, out);
}

// Round 4
// 277.828 us; speedup vs baseline: 1.9959x; 1.9959x over previous
//
#include <hip/hip_runtime.h>
#include <math.h>

#define WD 80
#define HW 6400
#define PW 82          // padded row width
#define PPX 6790       // allocated pixels per padded image (82*82=6724 + staging slack)
#define NIMG 8
#define NPAIR 32
#define RR 4           // output rows per tile
#define STG 960        // uint4 granules per staged buffer = (RR+2)*20*64*2/16

typedef short bf16x8 __attribute__((ext_vector_type(8)));
typedef float f32x4 __attribute__((ext_vector_type(4)));

__device__ __forceinline__ float bf2f(unsigned short u) {
    return __uint_as_float(((unsigned)u) << 16);
}
__device__ __forceinline__ unsigned short f2bf(float f) {
    unsigned u = __float_as_uint(f);
    u += 0x7fff + ((u >> 16) & 1);          // RNE
    return (unsigned short)(u >> 16);
}

// ---------------- transformation matrices (inverse affine) ----------------
__global__ void prep_mats(const float* __restrict__ P, float* __restrict__ mats) {
    int p = threadIdx.x;
    if (p >= NPAIR) return;
    const float* m = P + p * 16;
    float m00 = m[0], m01 = m[1], m02 = m[3] / 0.8f;
    float m10 = m[4], m11 = m[5], m12 = m[7] / 0.8f;
    float cx = 40.0f, cy = 40.0f;
    float tx = cx - (m00 * cx + m01 * cy) + m02;
    float ty = cy - (m10 * cx + m11 * cy) + m12;
    float det = m00 * m11 - m01 * m10;
    float id = 1.0f / det;
    float a00 =  m11 * id, a01 = -m01 * id;
    float a10 = -m10 * id, a11 =  m00 * id;
    float a02 = -(a00 * tx + a01 * ty);
    float a12 = -(a10 * tx + a11 * ty);
    float* o = mats + p * 6;
    o[0] = a00; o[1] = a01; o[2] = a02;
    o[3] = a10; o[4] = a11; o[5] = a12;
}

// ---------------- nearest-neighbor validity mask ----------------
__global__ void make_mask(const float* __restrict__ mats, float* __restrict__ mask) {
    int p = blockIdx.x;
    const float* a = mats + p * 6;
    float a0 = a[0], a1 = a[1], a2 = a[2], a3 = a[3], a4 = a[4], a5 = a[5];
    for (int q = threadIdx.x; q < HW; q += blockDim.x) {
        float x = (float)(q % WD), y = (float)(q / WD);
        float sx = a0 * x + a1 * y + a2;
        float sy = a3 * x + a4 * y + a5;
        int ix = (int)rintf(sx), iy = (int)rintf(sy);
        mask[p * HW + q] = (ix >= 0 && ix < WD && iy >= 0 && iy < WD) ? 1.0f : 0.0f;
    }
}

// ---------------- zero fill ----------------
__global__ void zero_u4(uint4* __restrict__ p, int n4) {
    int t = blockIdx.x * blockDim.x + threadIdx.x;
    if (t < n4) p[t] = (uint4){0, 0, 0, 0};
}

// ---------------- initial rotation via LDS transpose ----------------
// Y[img][a][b][c] = x[img][c][79-b][a].  Block = (img, hh): source plane-row hh of all 64 ch.
__global__ __launch_bounds__(256) void rot_init_t(const float* __restrict__ x,
                                                  unsigned short* __restrict__ Y) {
    __shared__ float T[64][81];
    int img = blockIdx.x / 80, hh = blockIdx.x % 80;
    int tid = threadIdx.x;
    for (int idx = tid; idx < 64 * 80; idx += 256) {
        int c = idx / 80, ww = idx % 80;
        T[c][ww] = x[((size_t)(img * 64 + c) * 80 + hh) * 80 + ww];
    }
    __syncthreads();
    int b = 79 - hh;
    for (int idx = tid; idx < 80 * 64; idx += 256) {
        int a = idx >> 6, ch = idx & 63;
        Y[((size_t)img * PPX + (a + 1) * PW + (b + 1)) * 64 + ch] = f2bf(T[ch][a]);
    }
}

// ---------------- weight repack: dst[tap][co][cin] bf16 ----------------
__global__ void prep_w(const float* __restrict__ src, unsigned short* __restrict__ dst,
                       int cin_n, int co_off, int ci_off, int co_stride) {
    int t = blockIdx.x * blockDim.x + threadIdx.x;
    if (t >= 9 * 64 * cin_n) return;
    int ci = t % cin_n;
    int co = (t / cin_n) & 63;
    int tap = t / (cin_n * 64);
    dst[t] = f2bf(src[(size_t)(co_off + co) * co_stride + (ci_off + ci) * 9 + tap]);
}

// ---------------- bilinear warp of pairs into padded warped[k] ----------------
__global__ void warp_pairs(const unsigned short* __restrict__ Ysrc, const float* __restrict__ mats,
                           unsigned short* __restrict__ warped, int total, int only0) {
    int idx = blockIdx.x * blockDim.x + threadIdx.x;
    if (idx >= total) return;
    int g = idx & 7;
    int pp = (idx >> 3) % 6724;
    int k = idx / (6724 * 8);
    int p = only0 ? k * 4 : k;
    int py = pp / PW, pxx = pp % PW;
    uint4 v = {0, 0, 0, 0};
    if (py >= 1 && py <= 80 && pxx >= 1 && pxx <= 80) {
        int y = py - 1, x = pxx - 1;
        const float* a = mats + p * 6;
        float sx = a[0] * x + a[1] * y + a[2];
        float sy = a[3] * x + a[4] * y + a[5];
        float fxf = floorf(sx), fyf = floorf(sy);
        float fx = sx - fxf, fy = sy - fyf;
        int ix = (int)fxf, iy = (int)fyf;
        float w00 = (1.f - fx) * (1.f - fy), w10 = fx * (1.f - fy);
        float w01 = (1.f - fx) * fy,         w11 = fx * fy;
        bool vx0 = (unsigned)ix < WD, vx1 = (unsigned)(ix + 1) < WD;
        bool vy0 = (unsigned)iy < WD, vy1 = (unsigned)(iy + 1) < WD;
        if (!(vx0 && vy0)) w00 = 0.f;
        if (!(vx1 && vy0)) w10 = 0.f;
        if (!(vx0 && vy1)) w01 = 0.f;
        if (!(vx1 && vy1)) w11 = 0.f;
        int cx0 = min(max(ix, 0), WD - 1), cx1 = min(max(ix + 1, 0), WD - 1);
        int cy0 = min(max(iy, 0), WD - 1), cy1 = min(max(iy + 1, 0), WD - 1);
        const unsigned short* src = Ysrc + (size_t)(p >> 2) * PPX * 64 + g * 8;
        uint4 c00 = *(const uint4*)(src + ((cy0 + 1) * PW + cx0 + 1) * 64);
        uint4 c10 = *(const uint4*)(src + ((cy0 + 1) * PW + cx1 + 1) * 64);
        uint4 c01 = *(const uint4*)(src + ((cy1 + 1) * PW + cx0 + 1) * 64);
        uint4 c11 = *(const uint4*)(src + ((cy1 + 1) * PW + cx1 + 1) * 64);
        const unsigned short* p00 = (const unsigned short*)&c00;
        const unsigned short* p10 = (const unsigned short*)&c10;
        const unsigned short* p01 = (const unsigned short*)&c01;
        const unsigned short* p11 = (const unsigned short*)&c11;
        unsigned short r8[8];
#pragma unroll
        for (int kk = 0; kk < 8; ++kk) {
            float vv = w00 * bf2f(p00[kk]) + w10 * bf2f(p10[kk])
                     + w01 * bf2f(p01[kk]) + w11 * bf2f(p11[kk]);
            r8[kk] = f2bf(vv);
        }
        v = *(const uint4*)r8;
    }
    *(uint4*)(warped + ((size_t)k * PPX + pp) * 64 + g * 8) = v;
}

// ---------------- async staged halo tile: (RR+2) rows x 20 px x 64 ch, swizzled ----------------
__device__ __forceinline__ void stage_t(const unsigned short* __restrict__ src,
                                        int x0, int y0, uint4* bufbase, int tid, int nw) {
    const int lane = tid & 63;
    const int wv = tid >> 6;
    for (int c = wv; c < STG / 64; c += nw) {
        int s = c * 64 + lane;
        int q = s >> 3;
        int yl = q / 20, xl = q - yl * 20;
        int g = (s & 7) ^ (q & 7);
        const unsigned short* gp = src + ((y0 + yl) * PW + x0 + xl) * 64 + g * 8;
        __builtin_amdgcn_global_load_lds(
            (const __attribute__((address_space(1))) unsigned int*)gp,
            (__attribute__((address_space(3))) unsigned int*)(bufbase + c * 64),
            16, 0, 0);
    }
}

// ---------------- load 18 B-fragments (9 taps x 2 k-slices) into VGPRs ----------------
__device__ __forceinline__ void load_w(const unsigned short* __restrict__ W, int row,
                                       int cinstride, int cin0, int lh, bf16x8* Wf) {
#pragma unroll
    for (int ks = 0; ks < 2; ++ks)
#pragma unroll
        for (int tap = 0; tap < 9; ++tap)
            Wf[ks * 9 + tap] = *(const bf16x8*)(W + (size_t)(tap * 64 + row) * cinstride
                                                + cin0 + ks * 32 + lh * 8);
}

// ---------------- conv pass: 72 MFMA from LDS tile, weights in regs ----------------
__device__ __forceinline__ void conv_pass(const uint4* __restrict__ buf, const bf16x8* Wf,
                                          int ll, int lh, f32x4* acc) {
#pragma unroll
    for (int ks = 0; ks < 2; ++ks) {
        int g = ks * 4 + lh;
#pragma unroll
        for (int tap = 0; tap < 9; ++tap) {
            bf16x8 B = Wf[ks * 9 + tap];
            int ty = tap / 3, tx = tap % 3;
#pragma unroll
            for (int r = 0; r < RR; ++r) {
                int q = (r + ty) * 20 + tx + ll;
                bf16x8 A = *(const bf16x8*)&buf[q * 8 + (g ^ (q & 7))];
                acc[r] = __builtin_amdgcn_mfma_f32_16x16x32_bf16(A, B, acc[r], 0, 0, 0);
            }
        }
    }
}

// ---------------- agg (+ fused ego): Gpad = 0.25*(sum_i m_i*conv_n(warp_i) + (sum m_i)*(conv_e(y)+b)) ----------------
__global__ __launch_bounds__(256) void msg_agg(const unsigned short* __restrict__ warped,
        const unsigned short* __restrict__ Y, const float* __restrict__ mask,
        const unsigned short* __restrict__ Wn, const unsigned short* __restrict__ We,
        const float* __restrict__ bias, unsigned short* __restrict__ Gpad, int only0) {
    __shared__ uint4 lds[2 * STG];
    __shared__ float lmask[4][RR][16];
    const int tid = threadIdx.x, lane = tid & 63, wv = tid >> 6;
    const int ll = lane & 15, lh = lane >> 4;
    const int x0 = blockIdx.x * 16, y0 = blockIdx.y * RR;
    const int t = blockIdx.z;
    const int b = only0 ? t : (t >> 2), j = only0 ? 0 : (t & 3);
    const int row = wv * 16 + ll;       // co = cg*16 + ll, cg = wave id

    int ks_[4], ps_[4];
#pragma unroll
    for (int i = 0; i < 4; ++i) {
        int k = only0 ? (b * 4 + i) : ((b * 4 + i) * 4 + j);
        ks_[i] = k; ps_[i] = only0 ? k * 4 : k;
    }
    for (int idx = tid; idx < 4 * RR * 16; idx += 256) {
        int i = idx / (RR * 16), r = (idx >> 4) % RR, px = idx & 15;
        lmask[i][r][px] = mask[(size_t)ps_[i] * HW + (y0 + r) * WD + x0 + px];
    }
    bf16x8 Wf[18];
    load_w(Wn, row, 64, 0, lh, Wf);
    stage_t(warped + (size_t)ks_[0] * PPX * 64, x0, y0, lds, tid, 4);
    __syncthreads();

    f32x4 tot[RR];
#pragma unroll
    for (int r = 0; r < RR; ++r) tot[r] = (f32x4){0.f, 0.f, 0.f, 0.f};

    for (int i = 0; i < 4; ++i) {
        if (i < 3)
            stage_t(warped + (size_t)ks_[i + 1] * PPX * 64, x0, y0, lds + ((i + 1) & 1) * STG, tid, 4);
        f32x4 acc[RR];
#pragma unroll
        for (int r = 0; r < RR; ++r) acc[r] = (f32x4){0.f, 0.f, 0.f, 0.f};
        conv_pass(lds + (i & 1) * STG, Wf, ll, lh, acc);
#pragma unroll
        for (int r = 0; r < RR; ++r)
#pragma unroll
            for (int jj = 0; jj < 4; ++jj)
                tot[r][jj] += lmask[i][r][lh * 4 + jj] * acc[r][jj];
        __syncthreads();
    }

    // fused ego pass
    load_w(We, row, 64, 0, lh, Wf);
    const int img = only0 ? t * 4 : t;
    stage_t(Y + (size_t)img * PPX * 64, x0, y0, lds, tid, 4);
    __syncthreads();
    f32x4 acc[RR];
#pragma unroll
    for (int r = 0; r < RR; ++r) acc[r] = (f32x4){0.f, 0.f, 0.f, 0.f};
    conv_pass(lds, Wf, ll, lh, acc);

    float bv = bias[row];
#pragma unroll
    for (int r = 0; r < RR; ++r)
#pragma unroll
        for (int jj = 0; jj < 4; ++jj) {
            int px = lh * 4 + jj;
            float msum = lmask[0][r][px] + lmask[1][r][px] + lmask[2][r][px] + lmask[3][r][px];
            float val = 0.25f * (tot[r][jj] + msum * (acc[r][jj] + bv));
            Gpad[((size_t)t * PPX + (y0 + r + 1) * PW + (x0 + px + 1)) * 64 + row] = f2bf(val);
        }
}

// ---------------- fused GRU conv: h1 = sigmoid(convU)+ * tanh(convC), 8 waves ----------------
__global__ __launch_bounds__(512) void gru_conv(const unsigned short* __restrict__ Ysrc,
        const unsigned short* __restrict__ Gpad,
        const unsigned short* __restrict__ Wu, const unsigned short* __restrict__ Wc,
        const float* __restrict__ bu, const float* __restrict__ bc,
        unsigned short* __restrict__ Ydst, int only0) {
    __shared__ uint4 lds[2 * STG];
    const int tid = threadIdx.x, lane = tid & 63, w8 = tid >> 6;
    const int ll = lane & 15, lh = lane >> 4;
    const int strm = w8 >> 2, cg = w8 & 3;
    const int x0 = blockIdx.x * 16, y0 = blockIdx.y * RR;
    const int t = blockIdx.z;
    const int img = only0 ? t * 4 : t;
    const int row = cg * 16 + ll;
    const unsigned short* W = strm ? Wc : Wu;

    stage_t(Ysrc + (size_t)img * PPX * 64, x0, y0, lds, tid, 8);
    stage_t(Gpad + (size_t)t * PPX * 64, x0, y0, lds + STG, tid, 8);
    bf16x8 Wf[18];
    load_w(W, row, 128, 0, lh, Wf);
    __syncthreads();

    f32x4 acc[RR];
#pragma unroll
    for (int r = 0; r < RR; ++r) acc[r] = (f32x4){0.f, 0.f, 0.f, 0.f};
    conv_pass(lds, Wf, ll, lh, acc);
    load_w(W, row, 128, 64, lh, Wf);
    conv_pass(lds + STG, Wf, ll, lh, acc);
    __syncthreads();                 // all LDS reads done; tile space now dead

    float* sig = (float*)lds;        // RR*16*64 f32 = 16 KB, fits in dead tile space
    float bv = strm ? bc[row] : bu[row];
    if (strm == 0) {
#pragma unroll
        for (int r = 0; r < RR; ++r)
#pragma unroll
            for (int jj = 0; jj < 4; ++jj) {
                float u = 1.f / (1.f + __expf(-(acc[r][jj] + bv)));
                sig[(r * 16 + lh * 4 + jj) * 64 + row] = u;
            }
    }
    __syncthreads();
    if (strm == 1) {
#pragma unroll
        for (int r = 0; r < RR; ++r)
#pragma unroll
            for (int jj = 0; jj < 4; ++jj) {
                float c = tanhf(acc[r][jj] + bv);
                float u = sig[(r * 16 + lh * 4 + jj) * 64 + row];
                Ydst[((size_t)img * PPX + (y0 + r + 1) * PW + (x0 + lh * 4 + jj + 1)) * 64 + row]
                    = f2bf(u * c);
            }
    }
}

// ---------------- final: out[b,h,w,o] = sum_c Ypad[4b][w][79-h][c]*mlp_w[o,c] + mlp_b[o] ----------------
__global__ void final_mlp(const unsigned short* __restrict__ yfin, const float* __restrict__ mw,
                          const float* __restrict__ mb, float* __restrict__ out) {
    int t = blockIdx.x * blockDim.x + threadIdx.x;
    if (t >= 2 * HW * 64) return;
    int o  = t & 63;
    int wv = (t >> 6) % WD;
    int h  = ((t >> 6) / WD) % WD;
    int b  = t / (HW * 64);
    const unsigned short* src = yfin + ((size_t)(b * 4) * PPX + (wv + 1) * PW + (80 - h)) * 64;
    float r = mb[o];
#pragma unroll 8
    for (int c = 0; c < 64; ++c) r += bf2f(src[c]) * mw[o * 64 + c];
    out[t] = r;
}

extern "C" void kernel_launch(void* const* d_in, const int* in_sizes, int n_in,
                              void* d_out, int out_size, void* d_ws, size_t ws_size,
                              hipStream_t stream) {
    const float* x       = (const float*)d_in[0];
    const float* P       = (const float*)d_in[2];
    const float* msg_w   = (const float*)d_in[4];
    const float* msg_b   = (const float*)d_in[5];
    const float* gates_w = (const float*)d_in[6];
    const float* gates_b = (const float*)d_in[7];
    const float* can_w   = (const float*)d_in[8];
    const float* can_b   = (const float*)d_in[9];
    const float* mlp_w   = (const float*)d_in[10];
    const float* mlp_b   = (const float*)d_in[11];
    float* out = (float*)d_out;

    char* wsb = (char*)d_ws;
    float* mats = (float*)wsb;                              // 1024 B
    float* mask = (float*)(wsb + 1024);                     // 819200
    unsigned short* Wn = (unsigned short*)(wsb + 820224);   // 73728
    unsigned short* We = Wn + 36864;                        // 73728
    unsigned short* Wu = We + 36864;                        // 147456
    unsigned short* Wc = Wu + 73728;                        // 147456
    unsigned short* Y0 = Wc + 73728;                        // 8*PPX*128 = 6952960
    unsigned short* Y1 = Y0 + (size_t)NIMG * PPX * 64;      // 6952960
    unsigned short* warped = Y1 + (size_t)NIMG * PPX * 64;  // 32*PPX*128 = 27811840
    unsigned short* Gpad = warped + (size_t)NPAIR * PPX * 64; // 6952960  (total ~50 MB)

    prep_mats<<<1, 64, 0, stream>>>(P, mats);
    make_mask<<<NPAIR, 256, 0, stream>>>(mats, mask);
    prep_w<<<(9 * 64 * 64 + 255) / 256, 256, 0, stream>>>(msg_w, Wn, 64, 0, 0, 1152);
    prep_w<<<(9 * 64 * 64 + 255) / 256, 256, 0, stream>>>(msg_w, We, 64, 0, 64, 1152);
    prep_w<<<(9 * 64 * 128 + 255) / 256, 256, 0, stream>>>(gates_w, Wu, 128, 64, 0, 1728);
    prep_w<<<(9 * 64 * 128 + 255) / 256, 256, 0, stream>>>(can_w, Wc, 128, 0, 0, 1728);
    {   // zero Y0+Y1 (contiguous) and Gpad: borders must be exact zeros for SAME conv
        int n4a = (int)((size_t)2 * NIMG * PPX * 64 * 2 / 16);
        int n4b = (int)((size_t)NIMG * PPX * 64 * 2 / 16);
        zero_u4<<<(n4a + 255) / 256, 256, 0, stream>>>((uint4*)Y0, n4a);
        zero_u4<<<(n4b + 255) / 256, 256, 0, stream>>>((uint4*)Gpad, n4b);
    }
    rot_init_t<<<NIMG * 80, 256, 0, stream>>>(x, Y0);

    // ---- iteration 0 (all 8 targets) ----
    warp_pairs<<<(32 * 6724 * 8 + 255) / 256, 256, 0, stream>>>(Y0, mats, warped, 32 * 6724 * 8, 0);
    msg_agg<<<dim3(5, 80 / RR, 8), 256, 0, stream>>>(warped, Y0, mask, Wn, We, msg_b, Gpad, 0);
    gru_conv<<<dim3(5, 80 / RR, 8), 512, 0, stream>>>(Y0, Gpad, Wu, Wc, gates_b + 64, can_b, Y1, 0);

    // ---- iteration 1 (only j=0 targets: images 0 and 4) ----
    warp_pairs<<<(8 * 6724 * 8 + 255) / 256, 256, 0, stream>>>(Y1, mats, warped, 8 * 6724 * 8, 1);
    msg_agg<<<dim3(5, 80 / RR, 2), 256, 0, stream>>>(warped, Y1, mask, Wn, We, msg_b, Gpad, 1);
    gru_conv<<<dim3(5, 80 / RR, 2), 512, 0, stream>>>(Y1, Gpad, Wu, Wc, gates_b + 64, can_b, Y0, 1);

    final_mlp<<<(2 * HW * 64 + 255) / 256, 256, 0, stream>>>(Y0, mlp_w, mlp_b, out);
}